// Round 11
// baseline (251.746 us; speedup 1.0000x reference)
//
#include <hip/hip_runtime.h>
#include <math.h>

#define TT 512
#define DD 256
#define BIGF 9999.0f
#define KK 8

// ws layout (bytes)
#define HT_OFF    0          // float ht[DD][TT]   512 KB  transposed H
#define A_OFF     524288     // float a[TT]
#define B_OFF     526336     // float b[TT]
#define MB_OFF    528384     // ull   mb[TT][4]
#define MSEP_OFF  544768     // float msep4[128]

typedef unsigned long long ull;

__global__ __launch_bounds__(256) void prep_kernel(
    const float* __restrict__ X, const float* __restrict__ H,
    const float* __restrict__ C, const int* __restrict__ M,
    float* __restrict__ ht, float* __restrict__ A, float* __restrict__ B,
    ull* __restrict__ MB, float* __restrict__ MSEP4, float* __restrict__ out) {
  const int b = blockIdx.x;
  const int t = threadIdx.x;
  const int wid = t >> 6, lane = t & 63;
  const int i0 = 4 * b;
  if (b == 0 && t == 0) out[0] = 0.0f;  // re-arm accumulator every call

  __shared__ float sA[4][4], sB[4][4], sM[4][4];
  float hv[4];
#pragma unroll
  for (int r = 0; r < 4; ++r) {
    const int idx = (i0 + r) * DD + t;
    const float x = X[idx], h = H[idx], c = C[idx];
    const int m = M[idx];
    hv[r] = h;
    const float e = m ? (x - h + c) : 0.0f;
    float pm = e * e, ph = h, ph2 = h * h;
#pragma unroll
    for (int s = 1; s < 64; s <<= 1) {
      pm  += __shfl_xor(pm, s);
      ph  += __shfl_xor(ph, s);
      ph2 += __shfl_xor(ph2, s);
    }
    const ull bal = __ballot(m != 0);
    if (lane == 0) {
      sA[r][wid] = ph; sB[r][wid] = ph2; sM[r][wid] = pm;
      MB[(i0 + r) * 4 + wid] = bal;
    }
  }
  // transpose write: ht[d=t][i0..i0+3], 16B aligned
  *(float4*)(ht + t * TT + i0) = make_float4(hv[0], hv[1], hv[2], hv[3]);
  __syncthreads();
  if (t < 4) {
    A[i0 + t] = sA[t][0] + sA[t][1] + sA[t][2] + sA[t][3];
    B[i0 + t] = sB[t][0] + sB[t][1] + sB[t][2] + sB[t][3];
  }
  if (t == 0) {
    float ms = 0.0f;
#pragma unroll
    for (int r = 0; r < 4; ++r)
#pragma unroll
      for (int wq = 0; wq < 4; ++wq) ms += sM[r][wq];
    MSEP4[b] = ms;
  }
}

// 256 blocks x 256 threads, __launch_bounds__(256,1): full VGPR file for a
// 2-buffer 16-deep software pipeline. Block owns rows {2b,2b+1}; thread t
// owns j={2t,2t+1}. i-operand via LDS broadcast; j-operand coalesced from ht.
#define BT 16  // batch depth
__global__ __launch_bounds__(256, 1) void score_kernel(
    const float* __restrict__ H, const float* __restrict__ ht,
    const float* __restrict__ A, const float* __restrict__ B,
    const ull* __restrict__ MB, const float* __restrict__ MSEP4,
    float* __restrict__ out) {
  __shared__ float2 hi2[DD];      // 2 KB: both i-rows at each d
  __shared__ float dl[2][TT];     // 4 KB scores
  __shared__ float nrm[2][TT];    // 4 KB norms
  __shared__ float s_rl[2];

  const int b = blockIdx.x;
  const int t = threadIdx.x;
  const int wv = t >> 6, lane = t & 63;
  const int i0 = 2 * b;

  // stage the 2 i-rows into LDS (coalesced)
  {
    const float v0 = H[i0 * DD + t];
    const float v1 = H[(i0 + 1) * DD + t];
    hi2[t] = make_float2(v0, v1);
  }
  __syncthreads();

  // dot phase: explicit 2-buffer 16-deep pipeline (all indices compile-time)
  float acc00 = 0.f, acc01 = 0.f, acc10 = 0.f, acc11 = 0.f;
  {
    const float* __restrict__ pj = ht + 2 * t;
    float2 JA[BT], JB[BT], IA[BT], IB[BT];
#pragma unroll
    for (int k = 0; k < BT; ++k) {         // prologue: batch 0 -> A buffers
      JA[k] = *(const float2*)(pj + k * TT);
      IA[k] = hi2[k];
    }
#pragma unroll
    for (int bt = 0; bt < DD / BT; ++bt) {
      if (bt < DD / BT - 1) {              // issue batch bt+1 into other buf
#pragma unroll
        for (int k = 0; k < BT; ++k) {
          const int d = (bt + 1) * BT + k;
          if ((bt & 1) == 0) {
            JB[k] = *(const float2*)(pj + d * TT);
            IB[k] = hi2[d];
          } else {
            JA[k] = *(const float2*)(pj + d * TT);
            IA[k] = hi2[d];
          }
        }
      }
#pragma unroll
      for (int k = 0; k < BT; ++k) {       // consume batch bt
        const float2 hj = ((bt & 1) == 0) ? JA[k] : JB[k];
        const float2 hi = ((bt & 1) == 0) ? IA[k] : IB[k];
        acc00 += hi.x * hj.x; acc01 += hi.x * hj.y;
        acc10 += hi.y * hj.x; acc11 += hi.y * hj.y;
      }
    }
  }

  // scores + norms for (i0..i0+1, j={2t,2t+1})
  {
    const float ai0 = A[i0], ai1 = A[i0 + 1];
    const float bi0 = B[i0], bi1 = B[i0 + 1];
    const ull n00 = MB[i0 * 4 + 0], n01 = MB[i0 * 4 + 1],
              n02 = MB[i0 * 4 + 2], n03 = MB[i0 * 4 + 3];
    const ull n10 = MB[(i0 + 1) * 4 + 0], n11 = MB[(i0 + 1) * 4 + 1],
              n12 = MB[(i0 + 1) * 4 + 2], n13 = MB[(i0 + 1) * 4 + 3];
#pragma unroll
    for (int jj = 0; jj < 2; ++jj) {
      const int j = 2 * t + jj;
      const float aj = A[j], bj = B[j];
      const ull m0 = MB[j * 4 + 0], m1 = MB[j * 4 + 1],
                m2 = MB[j * 4 + 2], m3 = MB[j * 4 + 3];
      const float dot0 = jj ? acc01 : acc00;
      const float dot1 = jj ? acc11 : acc10;
      {
        const float s2 = bi0 + bj - 2.0f * dot0;
        const float s1 = ai0 - aj;
        const float var = (s2 - s1 * s1 * (1.0f / DD)) * (1.0f / (DD - 1));
        const bool diff = (m0 != n00) | (m1 != n01) | (m2 != n02) | (m3 != n03);
        const bool valid = diff && (j != i0);
        dl[0][j] = valid ? sqrtf(fmaxf(var, 0.0f)) : BIGF;
        nrm[0][j] = sqrtf(fmaxf(s2, 0.0f));
      }
      {
        const float s2 = bi1 + bj - 2.0f * dot1;
        const float s1 = ai1 - aj;
        const float var = (s2 - s1 * s1 * (1.0f / DD)) * (1.0f / (DD - 1));
        const bool diff = (m0 != n10) | (m1 != n11) | (m2 != n12) | (m3 != n13);
        const bool valid = diff && (j != i0 + 1);
        dl[1][j] = valid ? sqrtf(fmaxf(var, 0.0f)) : BIGF;
        nrm[1][j] = sqrtf(fmaxf(s2, 0.0f));
      }
    }
  }
  __syncthreads();

  // waves 0-1: per-row iterative top-8 smallest (lowest-index tie-break)
  if (wv < 2) {
    const int w = wv;
    float cv[8];
#pragma unroll
    for (int c = 0; c < 8; ++c) cv[c] = dl[w][lane + 64 * c];

    float kv[KK];
    int ki[KK];
#pragma unroll
    for (int k = 0; k < KK; ++k) {
      float bv = cv[0];
      int bc = 0;
#pragma unroll
      for (int c = 1; c < 8; ++c) {
        if (cv[c] < bv) { bv = cv[c]; bc = c; }
      }
      int bidx = lane + 64 * bc;
#pragma unroll
      for (int s = 1; s < 64; s <<= 1) {
        const float ov = __shfl_xor(bv, s);
        const int oi = __shfl_xor(bidx, s);
        if (ov < bv || (ov == bv && oi < bidx)) { bv = ov; bidx = oi; }
      }
      kv[k] = bv;
      ki[k] = bidx;
      const int csel = bidx >> 6;
      const bool mine = (bidx & 63) == lane;
#pragma unroll
      for (int c = 0; c < 8; ++c) {
        if (mine && c == csel) cv[c] = BIGF;
      }
    }
    float wsum = 0.0f, rl = 0.0f;
#pragma unroll
    for (int k = 0; k < KK; ++k) {
      const float e = expf(kv[0] - kv[k]);  // kv[0] = min score
      wsum += e;
      rl += e * nrm[w][ki[k]];
    }
    if (lane == 0) s_rl[w] = rl / wsum;
  }
  __syncthreads();

  if (t == 0) {
    float part = s_rl[0] + s_rl[1];
    if ((b & 1) == 0) part += MSEP4[b >> 1];  // 4-row MSE group on even blocks
    atomicAdd(out, part);
  }
}

extern "C" void kernel_launch(void* const* d_in, const int* in_sizes, int n_in,
                              void* d_out, int out_size, void* d_ws, size_t ws_size,
                              hipStream_t stream) {
  const float* X = (const float*)d_in[0];
  const float* H = (const float*)d_in[1];
  const float* C = (const float*)d_in[2];
  const int* M = (const int*)d_in[3];
  float* out = (float*)d_out;

  char* ws = (char*)d_ws;
  float* ht = (float*)(ws + HT_OFF);
  float* A = (float*)(ws + A_OFF);
  float* B = (float*)(ws + B_OFF);
  ull* MB = (ull*)(ws + MB_OFF);
  float* MSEP4 = (float*)(ws + MSEP_OFF);

  prep_kernel<<<128, 256, 0, stream>>>(X, H, C, M, ht, A, B, MB, MSEP4, out);
  score_kernel<<<256, 256, 0, stream>>>(H, ht, A, B, MB, MSEP4, out);
}

// Round 12
// 23.176 us; speedup vs baseline: 10.8623x; 10.8623x over previous
//
#include <hip/hip_runtime.h>
#include <math.h>

#define TT 512
#define DD 256
#define BIGF 9999.0f
#define KK 8

typedef unsigned long long ull;
typedef __attribute__((ext_vector_type(8))) short s16x8;
typedef __attribute__((ext_vector_type(4))) float f32x4;

// ws layout (bytes)
#define HB_OFF   0            // ushort Hb[512][256]  bf16, K-swizzled, 256 KB
#define G_OFF    262144       // float  G[512][512]   1 MB
#define A_OFF    1310720      // float  a[512]
#define B_OFF    1312768      // float  b[512]
#define MB_OFF   1314816      // ull    mb[512][4]    16 KB
#define MSEP_OFF 1331200      // float  msep4[128]

__device__ __forceinline__ unsigned short toBf16(float f) {
  unsigned int u = __float_as_uint(f);
  unsigned int r = u + 0x7FFFu + ((u >> 16) & 1u);  // RNE
  return (unsigned short)(r >> 16);
}

__global__ __launch_bounds__(256) void prep_kernel(
    const float* __restrict__ X, const float* __restrict__ H,
    const float* __restrict__ C, const int* __restrict__ M,
    unsigned short* __restrict__ Hb, float* __restrict__ A,
    float* __restrict__ B, ull* __restrict__ MB, float* __restrict__ MSEP4,
    float* __restrict__ out) {
  const int b = blockIdx.x;
  const int t = threadIdx.x;
  const int wid = t >> 6, lane = t & 63;
  const int i0 = 4 * b;
  if (b == 0 && t == 0) out[0] = 0.0f;  // re-arm accumulator every call

  __shared__ float sA[4][4], sB[4][4], sM[4][4];
#pragma unroll
  for (int r = 0; r < 4; ++r) {
    const int row = i0 + r;
    const int idx = row * DD + t;
    const float x = X[idx], h = H[idx], c = C[idx];
    const int m = M[idx];
    // bf16 store, K-swizzled within 16B granules: dstk = t ^ ((row&7)<<3)
    const int dstk = t ^ ((row & 7) << 3);
    Hb[row * DD + dstk] = toBf16(h);
    const float e = m ? (x - h + c) : 0.0f;
    float pm = e * e, ph = h, ph2 = h * h;
#pragma unroll
    for (int s = 1; s < 64; s <<= 1) {
      pm  += __shfl_xor(pm, s);
      ph  += __shfl_xor(ph, s);
      ph2 += __shfl_xor(ph2, s);
    }
    const ull bal = __ballot(m != 0);
    if (lane == 0) {
      sA[r][wid] = ph; sB[r][wid] = ph2; sM[r][wid] = pm;
      MB[row * 4 + wid] = bal;
    }
  }
  __syncthreads();
  if (t < 4) {
    A[i0 + t] = sA[t][0] + sA[t][1] + sA[t][2] + sA[t][3];
    B[i0 + t] = sB[t][0] + sB[t][1] + sB[t][2] + sB[t][3];
  }
  if (t == 0) {
    float ms = 0.0f;
#pragma unroll
    for (int r = 0; r < 4; ++r)
#pragma unroll
      for (int wq = 0; wq < 4; ++wq) ms += sM[r][wq];
    MSEP4[b] = ms;
  }
}

// 64 blocks (8x8 tiles of 64x64), 256 threads (4 waves). K=256 fully
// LDS-resident. G = Hb . Hb^T via mfma_f32_16x16x32_bf16; symmetric, so any
// operand-transpose error is self-correcting. Swizzle (baked into Hb) makes
// fragment ds_read_b128 2-way-conflict-free.
__global__ __launch_bounds__(256, 2) void gram_kernel(
    const unsigned short* __restrict__ Hb, float* __restrict__ G) {
  __shared__ unsigned short At[64 * 256];  // 32 KB
  __shared__ unsigned short Bt[64 * 256];  // 32 KB
  const int t = threadIdx.x;
  const int lane = t & 63;
  const int wv = t >> 6;
  const int bx = blockIdx.x & 7, by = blockIdx.x >> 3;
  const int i0 = 64 * by, j0 = 64 * bx;

  // stage: flat 32KB copies (reg-staged; 16 independent loads, 1 vmcnt wait)
  {
    const s16x8* __restrict__ sa = (const s16x8*)(Hb + i0 * DD);
    const s16x8* __restrict__ sb = (const s16x8*)(Hb + j0 * DD);
    s16x8 va[8], vb[8];
#pragma unroll
    for (int q = 0; q < 8; ++q) va[q] = sa[q * 256 + t];
#pragma unroll
    for (int q = 0; q < 8; ++q) vb[q] = sb[q * 256 + t];
    s16x8* da = (s16x8*)At;
    s16x8* db = (s16x8*)Bt;
#pragma unroll
    for (int q = 0; q < 8; ++q) da[q * 256 + t] = va[q];
#pragma unroll
    for (int q = 0; q < 8; ++q) db[q * 256 + t] = vb[q];
  }
  __syncthreads();

  const int wr = wv >> 1, wc = wv & 1;  // wave quadrant (2x2 of 32x32)
  const int frow = lane & 15;
  const int kgrp = lane >> 4;           // 0..3
  const f32x4 zero = {0.f, 0.f, 0.f, 0.f};
  f32x4 acc[2][2];
  acc[0][0] = zero; acc[0][1] = zero; acc[1][0] = zero; acc[1][1] = zero;

#pragma unroll
  for (int ks = 0; ks < 8; ++ks) {
    s16x8 a[2], bfr[2];
#pragma unroll
    for (int m = 0; m < 2; ++m) {
      const int rr = 32 * wr + 16 * m + frow;
      const int g = (ks * 4 + kgrp) ^ (rr & 7);
      a[m] = *(const s16x8*)(At + rr * 256 + g * 8);
    }
#pragma unroll
    for (int n = 0; n < 2; ++n) {
      const int rr = 32 * wc + 16 * n + frow;
      const int g = (ks * 4 + kgrp) ^ (rr & 7);
      bfr[n] = *(const s16x8*)(Bt + rr * 256 + g * 8);
    }
#pragma unroll
    for (int m = 0; m < 2; ++m)
#pragma unroll
      for (int n = 0; n < 2; ++n)
        acc[m][n] = __builtin_amdgcn_mfma_f32_16x16x32_bf16(
            a[m], bfr[n], acc[m][n], 0, 0, 0);
  }

  // C/D mapping (m89-verified): col = lane&15, row = (lane>>4)*4 + reg
  const int crow0 = (lane >> 4) * 4;
  const int ccol = lane & 15;
#pragma unroll
  for (int m = 0; m < 2; ++m)
#pragma unroll
    for (int n = 0; n < 2; ++n)
#pragma unroll
      for (int r = 0; r < 4; ++r) {
        const int gr = i0 + 32 * wr + 16 * m + crow0 + r;
        const int gc = j0 + 32 * wc + 16 * n + ccol;
        G[gr * TT + gc] = acc[m][n][r];
      }
}

// 128 blocks x 256 threads. Block owns rows i0..i0+3; thread t owns
// j={2t,2t+1}. Dot comes from G (shallow float2 loads - no latency chain).
__global__ __launch_bounds__(256) void score_kernel(
    const float* __restrict__ G, const float* __restrict__ A,
    const float* __restrict__ B, const ull* __restrict__ MB,
    const float* __restrict__ MSEP4, float* __restrict__ out) {
  __shared__ float dl[4][TT];
  __shared__ float nrm[4][TT];
  __shared__ float s_rl[4];
  const int b = blockIdx.x;
  const int t = threadIdx.x;
  const int wid = t >> 6, lane = t & 63;
  const int i0 = 4 * b;

  float2 gv[4];
#pragma unroll
  for (int r = 0; r < 4; ++r)
    gv[r] = *(const float2*)(G + (i0 + r) * TT + 2 * t);

  float ai[4], bi[4];
  ull mi[4][4];
#pragma unroll
  for (int r = 0; r < 4; ++r) {
    ai[r] = A[i0 + r];
    bi[r] = B[i0 + r];
#pragma unroll
    for (int c = 0; c < 4; ++c) mi[r][c] = MB[(i0 + r) * 4 + c];
  }

#pragma unroll
  for (int jj = 0; jj < 2; ++jj) {
    const int j = 2 * t + jj;
    const float aj = A[j], bj = B[j];
    const ull m0 = MB[j * 4 + 0], m1 = MB[j * 4 + 1],
              m2 = MB[j * 4 + 2], m3 = MB[j * 4 + 3];
#pragma unroll
    for (int r = 0; r < 4; ++r) {
      const float dot = jj ? gv[r].y : gv[r].x;
      const float s2 = bi[r] + bj - 2.0f * dot;
      const float s1 = ai[r] - aj;
      const float var = (s2 - s1 * s1 * (1.0f / DD)) * (1.0f / (DD - 1));
      const bool diff = (m0 != mi[r][0]) | (m1 != mi[r][1]) |
                        (m2 != mi[r][2]) | (m3 != mi[r][3]);
      const bool valid = diff && (j != i0 + r);
      dl[r][j] = valid ? sqrtf(fmaxf(var, 0.0f)) : BIGF;
      nrm[r][j] = sqrtf(fmaxf(s2, 0.0f));
    }
  }
  __syncthreads();

  // wave w -> row i0+w: iterative top-8 smallest, lowest-index tie-break
  {
    const int w = wid;
    float cv[8];
#pragma unroll
    for (int c = 0; c < 8; ++c) cv[c] = dl[w][lane + 64 * c];

    float kv[KK];
    int ki[KK];
#pragma unroll
    for (int k = 0; k < KK; ++k) {
      float bv = cv[0];
      int bc = 0;
#pragma unroll
      for (int c = 1; c < 8; ++c) {
        if (cv[c] < bv) { bv = cv[c]; bc = c; }
      }
      int bidx = lane + 64 * bc;
#pragma unroll
      for (int s = 1; s < 64; s <<= 1) {
        const float ov = __shfl_xor(bv, s);
        const int oi = __shfl_xor(bidx, s);
        if (ov < bv || (ov == bv && oi < bidx)) { bv = ov; bidx = oi; }
      }
      kv[k] = bv;
      ki[k] = bidx;
      const int csel = bidx >> 6;
      const bool mine = (bidx & 63) == lane;
#pragma unroll
      for (int c = 0; c < 8; ++c) {
        if (mine && c == csel) cv[c] = BIGF;
      }
    }
    float wsum = 0.0f, rl = 0.0f;
#pragma unroll
    for (int k = 0; k < KK; ++k) {
      const float e = expf(kv[0] - kv[k]);  // kv[0] = min score
      wsum += e;
      rl += e * nrm[w][ki[k]];
    }
    if (lane == 0) s_rl[w] = rl / wsum;
  }
  __syncthreads();

  if (t == 0)
    atomicAdd(out, s_rl[0] + s_rl[1] + s_rl[2] + s_rl[3] + MSEP4[b]);
}

extern "C" void kernel_launch(void* const* d_in, const int* in_sizes, int n_in,
                              void* d_out, int out_size, void* d_ws, size_t ws_size,
                              hipStream_t stream) {
  const float* X = (const float*)d_in[0];
  const float* H = (const float*)d_in[1];
  const float* C = (const float*)d_in[2];
  const int* M = (const int*)d_in[3];
  float* out = (float*)d_out;

  char* ws = (char*)d_ws;
  unsigned short* Hb = (unsigned short*)(ws + HB_OFF);
  float* G = (float*)(ws + G_OFF);
  float* A = (float*)(ws + A_OFF);
  float* B = (float*)(ws + B_OFF);
  ull* MB = (ull*)(ws + MB_OFF);
  float* MSEP4 = (float*)(ws + MSEP_OFF);

  prep_kernel<<<128, 256, 0, stream>>>(X, H, C, M, Hb, A, B, MB, MSEP4, out);
  gram_kernel<<<64, 256, 0, stream>>>(Hb, G);
  score_kernel<<<128, 256, 0, stream>>>(G, A, B, MB, MSEP4, out);
}